// Round 5
// baseline (821.814 us; speedup 1.0000x reference)
//
#include <hip/hip_runtime.h>

#define F 64
#define BSH 7           // bucket = 128 dst nodes
#define BSZ 128

__device__ __forceinline__ float rlane(float v, int l) {
    return __uint_as_float(__builtin_amdgcn_readlane(__float_as_uint(v), l));
}

// ============ per-node in-degree ============
__global__ void k_count(const int* __restrict__ dst, int* count, int E) {
    int e = blockIdx.x * blockDim.x + threadIdx.x;
    if (e < E) atomicAdd(&count[dst[e]], 1);
}

__global__ void k_dis(const int* __restrict__ c, float* __restrict__ dis, int n) {
    int i = blockIdx.x * blockDim.x + threadIdx.x;
    if (i < n) dis[i] = rsqrtf((float)(c[i] + 1));
}

// ============ scan of PADDED counts -> row_start ============
__global__ void k_reduce(const int* __restrict__ c, int* __restrict__ bsum, int n) {
    __shared__ int s[256];
    int t = threadIdx.x;
    int i = blockIdx.x * 256 + t;
    s[t] = (i < n) ? ((c[i] + 15) & ~15) : 0;
    __syncthreads();
    for (int off = 128; off > 0; off >>= 1) {
        if (t < off) s[t] += s[t + off];
        __syncthreads();
    }
    if (t == 0) bsum[blockIdx.x] = s[0];
}

__global__ void k_scan_bsum(int* bs, int nb) {
    __shared__ int s[512];
    int t = threadIdx.x;
    int v = (t < nb) ? bs[t] : 0;
    s[t] = v;
    __syncthreads();
    for (int off = 1; off < 512; off <<= 1) {
        int x = (t >= off) ? s[t - off] : 0;
        __syncthreads();
        s[t] += x;
        __syncthreads();
    }
    if (t < nb) bs[t] = s[t] - v;  // exclusive
}

__global__ void k_scan_write(const int* __restrict__ c, const int* __restrict__ boff,
                             int* __restrict__ row_start, int n) {
    __shared__ int s[256];
    int t = threadIdx.x;
    int i = blockIdx.x * 256 + t;
    int v = (i < n) ? ((c[i] + 15) & ~15) : 0;
    s[t] = v;
    __syncthreads();
    for (int off = 1; off < 256; off <<= 1) {
        int x = (t >= off) ? s[t - off] : 0;
        __syncthreads();
        s[t] += x;
        __syncthreads();
    }
    if (i <= n) row_start[i] = s[t] - v + boff[blockIdx.x];
}

// ============ bucket (128-node) staging offsets ============
__global__ void k_bsum2(const int* __restrict__ count, int* __restrict__ bcnt, int n) {
    __shared__ int s[BSZ];
    int t = threadIdx.x;
    int i = (blockIdx.x << BSH) + t;
    s[t] = (i < n) ? count[i] : 0;
    __syncthreads();
    for (int off = BSZ / 2; off > 0; off >>= 1) {
        if (t < off) s[t] += s[t + off];
        __syncthreads();
    }
    if (t == 0) bcnt[blockIdx.x] = s[0];
}

// exclusive scan of bucket counts (nbkt <= 1024); also inits bucket cursors
__global__ void k_scan_b2(const int* __restrict__ bcnt, int* __restrict__ sb,
                          int* __restrict__ bcur, int nbkt) {
    __shared__ int s[1024];
    int t = threadIdx.x;
    int v = (t < nbkt) ? bcnt[t] : 0;
    s[t] = v;
    __syncthreads();
    for (int off = 1; off < 1024; off <<= 1) {
        int x = (t >= off) ? s[t - off] : 0;
        __syncthreads();
        s[t] += x;
        __syncthreads();
    }
    if (t <= nbkt) {
        int excl = s[t] - v;
        sb[t] = excl;
        if (t < nbkt) bcur[t] = excl;
    }
}

// ============ phase A: bin edges into bucket staging windows ============
__global__ void k_binA(const int* __restrict__ src, const int* __restrict__ dst,
                       int* bcur, int* __restrict__ stage, int E) {
    int e = blockIdx.x * blockDim.x + threadIdx.x;
    if (e < E) {
        int d = dst[e];
        int p = atomicAdd(&bcur[d >> BSH], 1);
        stage[p] = (src[e] << BSH) | (d & (BSZ - 1));
    }
}

// ============ phase B: per-bucket local scatter into padded CSR ============
__global__ __launch_bounds__(256) void k_binB(const int* __restrict__ stage,
                                              const int* __restrict__ sb,
                                              const int* __restrict__ row_start,
                                              int* __restrict__ csr, int n) {
    __shared__ int lcur[BSZ];
    int bk = blockIdx.x;
    int t = threadIdx.x;
    int base = bk << BSH;
    if (t < BSZ) {
        int node = base + t;
        lcur[t] = (node < n) ? row_start[node] : 0;
    }
    __syncthreads();
    int s0 = sb[bk], s1 = sb[bk + 1];
    for (int j = s0 + t; j < s1; j += 256) {
        int rec = stage[j];
        int p = atomicAdd(&lcur[rec & (BSZ - 1)], 1);
        csr[p] = rec >> BSH;
    }
    __syncthreads();
    // pad each row up to row_start[node+1] with zero-row index n (pad < 16)
    for (int q = t; q < BSZ * 16; q += 256) {
        int ln = q >> 4;
        int node = base + ln;
        if (node < n) {
            int slot = lcur[ln] + (q & 15);
            if (slot < row_start[node + 1]) csr[slot] = n;
        }
    }
}

// ============ hs0 = dis * x, zero row at index n ============
__global__ void k_prep(const float* __restrict__ x, const float* __restrict__ dis,
                       float* __restrict__ hs, int n) {
    int i = blockIdx.x * blockDim.x + threadIdx.x;
    int tot = (n + 1) * F;
    if (i >= tot) return;
    int row = i >> 6;
    hs[i] = (row < n) ? dis[row] * x[i] : 0.0f;
}

__global__ void k_zrow(float* __restrict__ hs, int n) {
    hs[(size_t)n * F + threadIdx.x] = 0.0f;
}

// ============ fused GCN layer: 4 rows per wave, DS-free gather ============
__global__ __launch_bounds__(256) void k_layer(const float* __restrict__ hin,
                                               const float* __restrict__ W,
                                               const float* __restrict__ b,
                                               const int* __restrict__ row_start,
                                               const int* __restrict__ csr,
                                               const float* __restrict__ dis,
                                               float* __restrict__ hout,
                                               int n, int scale_out) {
    __shared__ float Ws[F * F];
    int tid = threadIdx.x;
#pragma unroll
    for (int i = 0; i < 16; ++i) Ws[tid + i * 256] = W[tid + i * 256];
    __syncthreads();
    int lane = tid & 63;
    int r0 = (blockIdx.x * 4 + (tid >> 6)) * 4;
    if (r0 >= n) return;

    float acc0 = hin[((size_t)(r0 + 0) << 6) + lane];
    float acc1 = hin[((size_t)(r0 + 1) << 6) + lane];
    float acc2 = hin[((size_t)(r0 + 2) << 6) + lane];
    float acc3 = hin[((size_t)(r0 + 3) << 6) + lane];

    int s0 = row_start[r0];
    int s1 = row_start[r0 + 1];
    int s2 = row_start[r0 + 2];
    int s3 = row_start[r0 + 3];
    int s4 = row_start[r0 + 4];

    const int4* p4 = (const int4*)csr;
    for (int j = s0; j < s4; j += 16) {      // 16-batches are row-pure (pad-16)
        int g = j >> 2;
        int4 qa = p4[g], qb = p4[g + 1], qc = p4[g + 2], qd = p4[g + 3];
        float v0 = hin[((size_t)qa.x << 6) + lane];
        float v1 = hin[((size_t)qa.y << 6) + lane];
        float v2 = hin[((size_t)qa.z << 6) + lane];
        float v3 = hin[((size_t)qa.w << 6) + lane];
        float v4 = hin[((size_t)qb.x << 6) + lane];
        float v5 = hin[((size_t)qb.y << 6) + lane];
        float v6 = hin[((size_t)qb.z << 6) + lane];
        float v7 = hin[((size_t)qb.w << 6) + lane];
        float v8 = hin[((size_t)qc.x << 6) + lane];
        float v9 = hin[((size_t)qc.y << 6) + lane];
        float va = hin[((size_t)qc.z << 6) + lane];
        float vb = hin[((size_t)qc.w << 6) + lane];
        float vc = hin[((size_t)qd.x << 6) + lane];
        float vd = hin[((size_t)qd.y << 6) + lane];
        float ve = hin[((size_t)qd.z << 6) + lane];
        float vf = hin[((size_t)qd.w << 6) + lane];
        float t = (((v0 + v1) + (v2 + v3)) + ((v4 + v5) + (v6 + v7))) +
                  (((v8 + v9) + (va + vb)) + ((vc + vd) + (ve + vf)));
        if (j >= s3)      acc3 += t;
        else if (j >= s2) acc2 += t;
        else if (j >= s1) acc1 += t;
        else              acc0 += t;
    }

    acc0 *= dis[r0 + 0];
    acc1 *= dis[r0 + 1];
    acc2 *= dis[r0 + 2];
    acc3 *= dis[r0 + 3];

    float bb = b[lane];
    float y0 = bb, y1 = bb, y2 = bb, y3 = bb;
#pragma unroll
    for (int k = 0; k < F; ++k) {
        float w = Ws[(k << 6) + lane];
        y0 = fmaf(rlane(acc0, k), w, y0);
        y1 = fmaf(rlane(acc1, k), w, y1);
        y2 = fmaf(rlane(acc2, k), w, y2);
        y3 = fmaf(rlane(acc3, k), w, y3);
    }
    y0 = fmaxf(y0, 0.0f);
    y1 = fmaxf(y1, 0.0f);
    y2 = fmaxf(y2, 0.0f);
    y3 = fmaxf(y3, 0.0f);
    if (scale_out) {
        y0 *= dis[r0 + 0];
        y1 *= dis[r0 + 1];
        y2 *= dis[r0 + 2];
        y3 *= dis[r0 + 3];
    }
    hout[((size_t)(r0 + 0) << 6) + lane] = y0;
    hout[((size_t)(r0 + 1) << 6) + lane] = y1;
    hout[((size_t)(r0 + 2) << 6) + lane] = y2;
    hout[((size_t)(r0 + 3) << 6) + lane] = y3;
}

// ============ final 64->8 linear ============
__global__ __launch_bounds__(256) void k_final(const float* __restrict__ h,
                                               const float* __restrict__ Wl,
                                               const float* __restrict__ bl,
                                               float* __restrict__ out, int n) {
    __shared__ float Ws[F * 8];
    __shared__ float bs[8];
    int tid = threadIdx.x;
    Ws[tid] = Wl[tid];
    Ws[tid + 256] = Wl[tid + 256];
    if (tid < 8) bs[tid] = bl[tid];
    __syncthreads();
    int idx = blockIdx.x * 256 + tid;
    if (idx >= n * 8) return;
    int row = idx >> 3;
    int o = idx & 7;
    const float* hr = h + (size_t)row * F;
    float acc = bs[o];
#pragma unroll
    for (int k = 0; k < F; ++k) acc = fmaf(hr[k], Ws[k * 8 + o], acc);
    out[idx] = acc;
}

extern "C" void kernel_launch(void* const* d_in, const int* in_sizes, int n_in,
                              void* d_out, int out_size, void* d_ws, size_t ws_size,
                              hipStream_t stream) {
    const float* x  = (const float*)d_in[0];
    const int*   ei = (const int*)d_in[1];
    const float* W1 = (const float*)d_in[2];
    const float* b1 = (const float*)d_in[3];
    const float* W2 = (const float*)d_in[4];
    const float* b2 = (const float*)d_in[5];
    const float* W3 = (const float*)d_in[6];
    const float* b3 = (const float*)d_in[7];
    const float* Wl = (const float*)d_in[8];
    const float* bl = (const float*)d_in[9];
    float* out = (float*)d_out;

    int n = in_sizes[0] / F;   // 100000 (n % 4 == 0)
    int E = in_sizes[1] / 2;   // 1600000
    const int* src = ei;
    const int* dst = ei + E;

    int np   = (n + 256) & ~255;          // >= n+1, multiple of 256
    int nb   = (np + 255) / 256;          // <=512 for k_scan_bsum
    int nbkt = (n + BSZ - 1) >> BSH;      // 782 <= 1024 for k_scan_b2
    int cap  = E + 15 * n + 64;           // worst-case padded CSR size

    // workspace layout (4B elements): ~72 MB
    int*   count     = (int*)d_ws;
    int*   row_start = count + np;
    int*   bsum      = row_start + np;    // 512
    int*   bcnt      = bsum + 512;        // 1024
    int*   sb        = bcnt + 1024;       // 1025 -> pad 1040
    int*   bcur      = sb + 1040;         // 1024
    float* dis       = (float*)(bcur + 1024);
    int*   stage     = (int*)(dis + np);
    int*   csr       = stage + ((E + 3) & ~3);
    float* buf1      = (float*)(csr + ((cap + 3) & ~3));
    float* buf2      = buf1 + (size_t)(n + 1) * F;

    int nb_e = (E + 255) / 256;

    // ---- degree + norm ----
    hipMemsetAsync(count, 0, (size_t)np * sizeof(int), stream);
    k_count<<<nb_e, 256, 0, stream>>>(dst, count, E);
    k_dis<<<nb, 256, 0, stream>>>(count, dis, n);

    // ---- row_start = scan of padded counts ----
    k_reduce<<<nb, 256, 0, stream>>>(count, bsum, n);
    k_scan_bsum<<<1, 512, 0, stream>>>(bsum, nb);
    k_scan_write<<<nb, 256, 0, stream>>>(count, bsum, row_start, n);

    // ---- bucket staging offsets ----
    k_bsum2<<<nbkt, BSZ, 0, stream>>>(count, bcnt, n);
    k_scan_b2<<<1, 1024, 0, stream>>>(bcnt, sb, bcur, nbkt);

    // ---- binned CSR fill ----
    k_binA<<<nb_e, 256, 0, stream>>>(src, dst, bcur, stage, E);
    k_binB<<<nbkt, 256, 0, stream>>>(stage, sb, row_start, csr, n);

    // ---- hs0 = dis*x (row n zeroed) ----
    k_prep<<<((n + 1) * F + 255) / 256, 256, 0, stream>>>(x, dis, buf1, n);

    // ---- 3 fused layers, ping-pong ----
    int nb_l = (n / 4 + 3) / 4;
    k_layer<<<nb_l, 256, 0, stream>>>(buf1, W1, b1, row_start, csr, dis, buf2, n, 1);
    k_zrow<<<1, 64, 0, stream>>>(buf2, n);
    k_layer<<<nb_l, 256, 0, stream>>>(buf2, W2, b2, row_start, csr, dis, buf1, n, 1);
    k_layer<<<nb_l, 256, 0, stream>>>(buf1, W3, b3, row_start, csr, dis, buf2, n, 0);

    // ---- final linear ----
    k_final<<<(n * 8 + 255) / 256, 256, 0, stream>>>(buf2, Wl, bl, out, n);
}

// Round 6
// 415.928 us; speedup vs baseline: 1.9759x; 1.9759x over previous
//
#include <hip/hip_runtime.h>
#include <hip/hip_fp16.h>

#define F 64

__device__ __forceinline__ float rlane(float v, int l) {
    return __uint_as_float(__builtin_amdgcn_readlane(__float_as_uint(v), l));
}

// ============ per-node in-degree ============
__global__ void k_count(const int* __restrict__ dst, int* count, int E) {
    int e = blockIdx.x * blockDim.x + threadIdx.x;
    if (e < E) atomicAdd(&count[dst[e]], 1);
}

__global__ void k_dis(const int* __restrict__ c, float* __restrict__ dis, int n) {
    int i = blockIdx.x * blockDim.x + threadIdx.x;
    if (i < n) dis[i] = rsqrtf((float)(c[i] + 1));
}

// ============ scan of PADDED counts -> row_start, cursor ============
__global__ void k_reduce(const int* __restrict__ c, int* __restrict__ bsum, int n) {
    __shared__ int s[256];
    int t = threadIdx.x;
    int i = blockIdx.x * 256 + t;
    s[t] = (i < n) ? ((c[i] + 15) & ~15) : 0;
    __syncthreads();
    for (int off = 128; off > 0; off >>= 1) {
        if (t < off) s[t] += s[t + off];
        __syncthreads();
    }
    if (t == 0) bsum[blockIdx.x] = s[0];
}

__global__ void k_scan_bsum(int* bs, int nb) {
    __shared__ int s[512];
    int t = threadIdx.x;
    int v = (t < nb) ? bs[t] : 0;
    s[t] = v;
    __syncthreads();
    for (int off = 1; off < 512; off <<= 1) {
        int x = (t >= off) ? s[t - off] : 0;
        __syncthreads();
        s[t] += x;
        __syncthreads();
    }
    if (t < nb) bs[t] = s[t] - v;  // exclusive
}

__global__ void k_scan_write(const int* __restrict__ c, const int* __restrict__ boff,
                             int* __restrict__ row_start, int* __restrict__ cursor, int n) {
    __shared__ int s[256];
    int t = threadIdx.x;
    int i = blockIdx.x * 256 + t;
    int v = (i < n) ? ((c[i] + 15) & ~15) : 0;
    s[t] = v;
    __syncthreads();
    for (int off = 1; off < 256; off <<= 1) {
        int x = (t >= off) ? s[t - off] : 0;
        __syncthreads();
        s[t] += x;
        __syncthreads();
    }
    if (i <= n) {
        int excl = s[t] - v + boff[blockIdx.x];
        row_start[i] = excl;
        if (i < n) cursor[i] = excl;
    }
}

// pad slots point at the zero row n
__global__ void k_csr_init(int* __restrict__ csr, int n, int cap) {
    int i = blockIdx.x * blockDim.x + threadIdx.x;
    if (i < cap) csr[i] = n;
}

// ============ XCD-partitioned CSR fill ============
// Each edge chunk is visited by 8 blocks; block seg = blockIdx.x & 7 commits
// only dst in [seg*step, (seg+1)*step). With round-robin blockIdx->XCD
// dispatch, each XCD's scattered csr writes stay in a ~2.3 MB window that
// fits its 4 MB L2 (perf heuristic only; correctness is mapping-independent).
__global__ __launch_bounds__(256) void k_fillx(const int* __restrict__ src,
                                               const int* __restrict__ dst,
                                               int* cursor, int* __restrict__ csr,
                                               int E, int step) {
    int seg = blockIdx.x & 7;
    int e = (blockIdx.x >> 3) * 256 + threadIdx.x;
    if (e >= E) return;
    int d = dst[e];
    unsigned rel = (unsigned)(d - seg * step);
    if (rel < (unsigned)step) {
        int p = atomicAdd(&cursor[d], 1);
        csr[p] = src[e];
    }
}

// ============ hs0 = fp16(dis * x), zero row at index n ============
__global__ void k_prep(const float* __restrict__ x, const float* __restrict__ dis,
                       __half* __restrict__ hs, int n) {
    int i = blockIdx.x * blockDim.x + threadIdx.x;
    int tot = (n + 1) * F;
    if (i >= tot) return;
    int row = i >> 6;
    hs[i] = __float2half((row < n) ? dis[row] * x[i] : 0.0f);
}

__global__ void k_zrow(__half* __restrict__ hs, int n) {
    hs[(size_t)n * F + threadIdx.x] = __float2half(0.0f);
}

// ============ fused GCN layer: 4 rows/wave, fp16 storage, fp32 math ============
__global__ __launch_bounds__(256) void k_layer(const __half* __restrict__ hin,
                                               const float* __restrict__ W,
                                               const float* __restrict__ b,
                                               const int* __restrict__ row_start,
                                               const int* __restrict__ csr,
                                               const float* __restrict__ dis,
                                               __half* __restrict__ hout,
                                               int n, int scale_out) {
    __shared__ float Ws[F * F];
    int tid = threadIdx.x;
#pragma unroll
    for (int i = 0; i < 16; ++i) Ws[tid + i * 256] = W[tid + i * 256];
    __syncthreads();
    int lane = tid & 63;
    int r0 = (blockIdx.x * 4 + (tid >> 6)) * 4;
    if (r0 >= n) return;

    float acc0 = __half2float(hin[((size_t)(r0 + 0) << 6) + lane]);
    float acc1 = __half2float(hin[((size_t)(r0 + 1) << 6) + lane]);
    float acc2 = __half2float(hin[((size_t)(r0 + 2) << 6) + lane]);
    float acc3 = __half2float(hin[((size_t)(r0 + 3) << 6) + lane]);

    int s0 = row_start[r0];
    int s1 = row_start[r0 + 1];
    int s2 = row_start[r0 + 2];
    int s3 = row_start[r0 + 3];
    int s4 = row_start[r0 + 4];

    const int4* p4 = (const int4*)csr;
    for (int j = s0; j < s4; j += 16) {      // 16-batches are row-pure (pad-16)
        int g = j >> 2;
        int4 qa = p4[g], qb = p4[g + 1], qc = p4[g + 2], qd = p4[g + 3];
        float v0 = __half2float(hin[((size_t)qa.x << 6) + lane]);
        float v1 = __half2float(hin[((size_t)qa.y << 6) + lane]);
        float v2 = __half2float(hin[((size_t)qa.z << 6) + lane]);
        float v3 = __half2float(hin[((size_t)qa.w << 6) + lane]);
        float v4 = __half2float(hin[((size_t)qb.x << 6) + lane]);
        float v5 = __half2float(hin[((size_t)qb.y << 6) + lane]);
        float v6 = __half2float(hin[((size_t)qb.z << 6) + lane]);
        float v7 = __half2float(hin[((size_t)qb.w << 6) + lane]);
        float v8 = __half2float(hin[((size_t)qc.x << 6) + lane]);
        float v9 = __half2float(hin[((size_t)qc.y << 6) + lane]);
        float va = __half2float(hin[((size_t)qc.z << 6) + lane]);
        float vb = __half2float(hin[((size_t)qc.w << 6) + lane]);
        float vc = __half2float(hin[((size_t)qd.x << 6) + lane]);
        float vd = __half2float(hin[((size_t)qd.y << 6) + lane]);
        float ve = __half2float(hin[((size_t)qd.z << 6) + lane]);
        float vf = __half2float(hin[((size_t)qd.w << 6) + lane]);
        float t = (((v0 + v1) + (v2 + v3)) + ((v4 + v5) + (v6 + v7))) +
                  (((v8 + v9) + (va + vb)) + ((vc + vd) + (ve + vf)));
        if (j >= s3)      acc3 += t;
        else if (j >= s2) acc2 += t;
        else if (j >= s1) acc1 += t;
        else              acc0 += t;
    }

    acc0 *= dis[r0 + 0];
    acc1 *= dis[r0 + 1];
    acc2 *= dis[r0 + 2];
    acc3 *= dis[r0 + 3];

    float bb = b[lane];
    float y0 = bb, y1 = bb, y2 = bb, y3 = bb;
#pragma unroll
    for (int k = 0; k < F; ++k) {
        float w = Ws[(k << 6) + lane];
        y0 = fmaf(rlane(acc0, k), w, y0);
        y1 = fmaf(rlane(acc1, k), w, y1);
        y2 = fmaf(rlane(acc2, k), w, y2);
        y3 = fmaf(rlane(acc3, k), w, y3);
    }
    y0 = fmaxf(y0, 0.0f);
    y1 = fmaxf(y1, 0.0f);
    y2 = fmaxf(y2, 0.0f);
    y3 = fmaxf(y3, 0.0f);
    if (scale_out) {
        y0 *= dis[r0 + 0];
        y1 *= dis[r0 + 1];
        y2 *= dis[r0 + 2];
        y3 *= dis[r0 + 3];
    }
    hout[((size_t)(r0 + 0) << 6) + lane] = __float2half(y0);
    hout[((size_t)(r0 + 1) << 6) + lane] = __float2half(y1);
    hout[((size_t)(r0 + 2) << 6) + lane] = __float2half(y2);
    hout[((size_t)(r0 + 3) << 6) + lane] = __float2half(y3);
}

// ============ final 64->8 linear (fp16 input, fp32 math/out) ============
__global__ __launch_bounds__(256) void k_final(const __half* __restrict__ h,
                                               const float* __restrict__ Wl,
                                               const float* __restrict__ bl,
                                               float* __restrict__ out, int n) {
    __shared__ float Ws[F * 8];
    __shared__ float bs[8];
    int tid = threadIdx.x;
    Ws[tid] = Wl[tid];
    Ws[tid + 256] = Wl[tid + 256];
    if (tid < 8) bs[tid] = bl[tid];
    __syncthreads();
    int idx = blockIdx.x * 256 + tid;
    if (idx >= n * 8) return;
    int row = idx >> 3;
    int o = idx & 7;
    const __half* hr = h + (size_t)row * F;
    float acc = bs[o];
#pragma unroll
    for (int k = 0; k < F; ++k) acc = fmaf(__half2float(hr[k]), Ws[k * 8 + o], acc);
    out[idx] = acc;
}

extern "C" void kernel_launch(void* const* d_in, const int* in_sizes, int n_in,
                              void* d_out, int out_size, void* d_ws, size_t ws_size,
                              hipStream_t stream) {
    const float* x  = (const float*)d_in[0];
    const int*   ei = (const int*)d_in[1];
    const float* W1 = (const float*)d_in[2];
    const float* b1 = (const float*)d_in[3];
    const float* W2 = (const float*)d_in[4];
    const float* b2 = (const float*)d_in[5];
    const float* W3 = (const float*)d_in[6];
    const float* b3 = (const float*)d_in[7];
    const float* Wl = (const float*)d_in[8];
    const float* bl = (const float*)d_in[9];
    float* out = (float*)d_out;

    int n = in_sizes[0] / F;   // 100000 (n % 4 == 0)
    int E = in_sizes[1] / 2;   // 1600000
    const int* src = ei;
    const int* dst = ei + E;

    int np   = (n + 256) & ~255;          // >= n+1, multiple of 256
    int nb   = (np + 255) / 256;          // <=512 for k_scan_bsum
    int cap  = E + 15 * n + 64;           // worst-case padded CSR size
    int step = (n + 7) / 8;               // 12500 nodes per XCD segment

    // workspace layout: ints/halves, ~45 MB total
    int*    count     = (int*)d_ws;
    int*    row_start = count + np;
    int*    cursor    = row_start + np;
    int*    bsum      = cursor + np;      // 512
    float*  dis       = (float*)(bsum + 512);
    int*    csr       = (int*)(dis + np);
    __half* buf1      = (__half*)(csr + ((cap + 3) & ~3));
    __half* buf2      = buf1 + (size_t)(n + 1) * F;

    int nb_e = (E + 255) / 256;

    // ---- degree + norm ----
    hipMemsetAsync(count, 0, (size_t)np * sizeof(int), stream);
    k_count<<<nb_e, 256, 0, stream>>>(dst, count, E);
    k_dis<<<nb, 256, 0, stream>>>(count, dis, n);

    // ---- row_start/cursor = scan of padded counts ----
    k_reduce<<<nb, 256, 0, stream>>>(count, bsum, n);
    k_scan_bsum<<<1, 512, 0, stream>>>(bsum, nb);
    k_scan_write<<<nb, 256, 0, stream>>>(count, bsum, row_start, cursor, n);

    // ---- padded CSR fill (XCD-partitioned) ----
    k_csr_init<<<(cap + 255) / 256, 256, 0, stream>>>(csr, n, cap);
    k_fillx<<<8 * nb_e, 256, 0, stream>>>(src, dst, cursor, csr, E, step);

    // ---- hs0 = fp16(dis*x), row n zeroed ----
    k_prep<<<((n + 1) * F + 255) / 256, 256, 0, stream>>>(x, dis, buf1, n);

    // ---- 3 fused layers, ping-pong ----
    int nb_l = (n / 4 + 3) / 4;
    k_layer<<<nb_l, 256, 0, stream>>>(buf1, W1, b1, row_start, csr, dis, buf2, n, 1);
    k_zrow<<<1, 64, 0, stream>>>(buf2, n);
    k_layer<<<nb_l, 256, 0, stream>>>(buf2, W2, b2, row_start, csr, dis, buf1, n, 1);
    k_layer<<<nb_l, 256, 0, stream>>>(buf1, W3, b3, row_start, csr, dis, buf2, n, 0);

    // ---- final linear ----
    k_final<<<(n * 8 + 255) / 256, 256, 0, stream>>>(buf2, Wl, bl, out, n);
}